// Round 7
// baseline (2185.274 us; speedup 1.0000x reference)
//
#include <hip/hip_runtime.h>

typedef unsigned short u16;
typedef unsigned int u32;

#define DD 256

typedef short  s16x8 __attribute__((ext_vector_type(8)));
typedef short  s16x4 __attribute__((ext_vector_type(4)));
typedef float  f32x4 __attribute__((ext_vector_type(4)));

__device__ __forceinline__ float b2f(u16 u){
  union { u32 i; float f; } c; c.i = ((u32)u) << 16; return c.f;
}
// round-to-nearest-even f32 -> bf16 (finite inputs)
__device__ __forceinline__ u16 f2b(float f){
  union { float f; u32 i; } c; c.f = f;
  u32 b = c.i + 0x7FFFu + ((c.i >> 16) & 1u);
  return (u16)(b >> 16);
}

// keep the harness's expected symbol name alive
__global__ void NodeEncoder_72971494359603_kernel(){}

// ---------------- dtype probe ----------------
__global__ void probe_dtype(const u32* w, u32* flag){
  if (threadIdx.x == 0 && blockIdx.x == 0){
    int cnt = 0;
    for (int i = 0; i < 256; i++){
      u32 low = w[i] & 0xFFFFu;
      u32 e = (low >> 7) & 0xFFu;
      if (e >= 0x60u && e <= 0x7Eu) cnt++;
    }
    *flag = (cnt >= 192) ? 1u : 0u;
  }
}

__global__ void cvt_in(const void* src, u16* dst, int n, const u32* flag){
  int i = blockIdx.x * 256 + threadIdx.x;
  if (i < n){
    if (*flag){
      dst[i] = ((const u16*)src)[i];
    } else {
      dst[i] = f2b(((const float*)src)[i]);
    }
  }
}

__global__ void store_out(const u16* h, void* dout, int n, const u32* flag){
  int i = blockIdx.x * 256 + threadIdx.x;
  if (i < n){
    if (*flag){
      ((u16*)dout)[i] = h[i];
    } else {
      ((float*)dout)[i] = b2f(h[i]);
    }
  }
}

// ---------------- utility ----------------
__global__ void zero_int(int* p, int n){
  int i = blockIdx.x * 256 + threadIdx.x;
  if (i < n) p[i] = 0;
}

// TBL[(l*18 + a*3 + b)*256 + j] = ee1[l][a][j] + ee2[l][b][j]   (f32)
__global__ void build_table(const u16* ee1, const u16* ee2, float* TBL){
  int b = blockIdx.x;               // 0..89
  int l = b / 18, c = b % 18, a = c / 3, bb = c % 3;
  int j = threadIdx.x;
  TBL[b * DD + j] = b2f(ee1[(l * 6 + a) * DD + j]) + b2f(ee2[(l * 3 + bb) * DD + j]);
}

// ---------------- CSR build ----------------
__global__ void hist_kernel(const int* dst, int* counts, int E){
  int e = blockIdx.x * 256 + threadIdx.x;
  if (e < E) atomicAdd(&counts[dst[e]], 1);
}

__global__ void scan_sums(const int* counts, int* bsum, int N){
  __shared__ int red[256];
  int tid = threadIdx.x;
  int base = blockIdx.x * 1024;
  int s = 0;
  for (int i = tid; i < 1024; i += 256){
    int g = base + i;
    if (g < N) s += counts[g];
  }
  red[tid] = s;
  __syncthreads();
  for (int off = 128; off > 0; off >>= 1){
    if (tid < off) red[tid] += red[tid + off];
    __syncthreads();
  }
  if (tid == 0) bsum[blockIdx.x] = red[0];
}

__global__ void scan_top(int* bsum, int nb){
  if (threadIdx.x == 0 && blockIdx.x == 0){
    int acc = 0;
    for (int i = 0; i < nb; i++){ int t = bsum[i]; bsum[i] = acc; acc += t; }
  }
}

__global__ void scan_block(const int* counts, const int* bsum,
                           int* offsets, int* cursor, int N){
  __shared__ int tsum[256];
  int b = blockIdx.x;
  int tid = threadIdx.x;
  int base = b * 1024;
  int v0, v1, v2, v3;
  int g = base + tid * 4;
  v0 = (g + 0 < N) ? counts[g + 0] : 0;
  v1 = (g + 1 < N) ? counts[g + 1] : 0;
  v2 = (g + 2 < N) ? counts[g + 2] : 0;
  v3 = (g + 3 < N) ? counts[g + 3] : 0;
  tsum[tid] = v0 + v1 + v2 + v3;
  __syncthreads();
  for (int off = 1; off < 256; off <<= 1){
    int t = (tid >= off) ? tsum[tid - off] : 0;
    __syncthreads();
    tsum[tid] += t;
    __syncthreads();
  }
  int excl = (tid == 0 ? 0 : tsum[tid - 1]) + bsum[b];
  if (g + 0 < N){ offsets[g + 0] = excl; cursor[g + 0] = excl; } excl += v0;
  if (g + 1 < N){ offsets[g + 1] = excl; cursor[g + 1] = excl; } excl += v1;
  if (g + 2 < N){ offsets[g + 2] = excl; cursor[g + 2] = excl; } excl += v2;
  if (g + 3 < N){ offsets[g + 3] = excl; cursor[g + 3] = excl; }
}

// payload[pos] = src | ((ea0*3+ea1) << 17)
__global__ void fill_csr(const int* ei, const int* ea, int* cursor,
                         int* payload, int E){
  int e = blockIdx.x * 256 + threadIdx.x;
  if (e < E){
    int d = ei[E + e];
    int pos = atomicAdd(&cursor[d], 1);
    int a = ea[2 * e], bb = ea[2 * e + 1];
    payload[pos] = ei[e] | ((a * 3 + bb) << 17);
  }
}

// ---------------- node embedding ----------------
__global__ void node_embed(const int* x, const u16* xe1, const u16* xe2,
                           u16* out, int N){
  int idx = blockIdx.x * 256 + threadIdx.x;
  if (idx < N * DD){
    int n = idx >> 8, j = idx & 255;
    int x0 = x[2 * n], x1 = x[2 * n + 1];
    out[idx] = f2b(b2f(xe1[x0 * DD + j]) + b2f(xe2[x1 * DD + j]));
  }
}

// ---------------- B packing for MFMA fragments (batched over layers) ----
// Wp chunk layout: frag = (cblk*(K/32) + ksub); lane l of frag holds
// W[ksub*32 + (l>>4)*8 + e][cblk*16 + (l&15)], e=0..7.
__global__ void pack_B(const u16* __restrict__ W0, u16* __restrict__ Wp0, int K, int Nc){
  const u16* W = W0 + (size_t)blockIdx.y * K * Nc;
  u16* Wp = Wp0 + (size_t)blockIdx.y * K * Nc;
  int idx = blockIdx.x * 256 + threadIdx.x;
  int lane = idx & 63;
  int t = idx >> 6;
  int nk = K >> 5;
  int ksub = t % nk, cblk = t / nk;
  if (cblk >= (Nc >> 4)) return;
  int col = cblk * 16 + (lane & 15);
  int krow = ksub * 32 + (lane >> 4) * 8;
  u16* dst = Wp + (size_t)idx * 8;
#pragma unroll
  for (int e = 0; e < 8; e++)
    dst[e] = W[(size_t)(krow + e) * Nc + col];
}

// ---------------- fused layer: gather(+BN+relu) -> MLP -> BN partials ----
// One block = 32 nodes, 256 threads = 4 waves (wc = wave, all share rows).
// Phase 0: gather CSR sums into swizzled LDS A-tile (edge table read from
//   GLOBAL -> L1; payload/feat loads software-pipelined depth 2).
// Then: A-fragments loaded ONCE into registers (64 VGPR); LDS is reused
//   as double-buffered mid (overlay). Chunk loop: G2(c) || G1(c+1), one
//   barrier per chunk. Epilogue bounces h through LDS for coalesced 16B
//   stores + fused BN partial sums.
__global__ __launch_bounds__(256, 4)
void layer_fused(const u16* __restrict__ feat, const float* __restrict__ TBL,
                 const int* __restrict__ offsets, const int* __restrict__ counts,
                 const int* __restrict__ payload,
                 const u16* __restrict__ Wp1, const u16* __restrict__ bias1,
                 const u16* __restrict__ Wp2, const u16* __restrict__ bias2,
                 u16* __restrict__ H, float* __restrict__ partial, int npart, int M,
                 const float* __restrict__ sums, const u16* __restrict__ gamma,
                 const u16* __restrict__ beta, float invN, int apply_bn){
  __shared__ __align__(16) char LB[16384];   // As [32][256]b16 / Ms[2][32][128]b16
  int tid = threadIdx.x, lane = tid & 63, wave = tid >> 6;
  int wc = wave;                              // 4 waves across columns
  int row0 = blockIdx.x * 32;
  int lr = lane & 15, hi = lane >> 4;

  // ---- phase 0: gather into LB-as-As (wave handles rows wave*8..+7) ----
  {
    int c4 = lane * 4;
    float sc[4], sh[4];
    if (apply_bn){
#pragma unroll
      for (int e = 0; e < 4; e++){
        int j = c4 + e;
        float mean = sums[j] * invN;
        float var = sums[DD + j] * invN - mean * mean;
        if (var < 0.f) var = 0.f;
        float scl = rsqrtf(var + 1e-5f) * b2f(gamma[j]);
        sc[e] = scl; sh[e] = b2f(beta[j]) - mean * scl;
      }
    } else {
#pragma unroll
      for (int e = 0; e < 4; e++){ sc[e] = 1.f; sh[e] = 0.f; }
    }
    for (int u = 0; u < 8; u++){
      int r = wave * 8 + u;
      int n = row0 + r; if (n > M - 1) n = M - 1;  // tail rows duplicate (never stored)
      s16x4 sv = *(const s16x4*)(feat + (size_t)n * DD + c4);
      f32x4 tb = *(const f32x4*)(TBL + 12 * DD + c4);   // self-loop idx 12 (L1)
      float v0 = b2f((u16)sv[0]) * sc[0] + sh[0];
      float v1 = b2f((u16)sv[1]) * sc[1] + sh[1];
      float v2 = b2f((u16)sv[2]) * sc[2] + sh[2];
      float v3 = b2f((u16)sv[3]) * sc[3] + sh[3];
      if (apply_bn){
        v0 = fmaxf(v0, 0.f); v1 = fmaxf(v1, 0.f);
        v2 = fmaxf(v2, 0.f); v3 = fmaxf(v3, 0.f);
      }
      float a0 = v0 + tb[0], a1 = v1 + tb[1], a2 = v2 + tb[2], a3 = v3 + tb[3];
      int e0 = offsets[n], cnt = counts[n], eend = e0 + cnt;
      if (cnt > 0){
        // depth-2 pipelined edge loop
        int pl = payload[e0];
        s16x4 rv = *(const s16x4*)(feat + (size_t)(pl & 0x1FFFF) * DD + c4);
        f32x4 tv = *(const f32x4*)(TBL + (pl >> 17) * DD + c4);
        for (int e = e0; e < eend; e++){
          int pln = 0; s16x4 rvn; f32x4 tvn;
          if (e + 1 < eend){
            pln = payload[e + 1];
            rvn = *(const s16x4*)(feat + (size_t)(pln & 0x1FFFF) * DD + c4);
            tvn = *(const f32x4*)(TBL + (pln >> 17) * DD + c4);
          }
          float w0 = b2f((u16)rv[0]) * sc[0] + sh[0];
          float w1 = b2f((u16)rv[1]) * sc[1] + sh[1];
          float w2 = b2f((u16)rv[2]) * sc[2] + sh[2];
          float w3 = b2f((u16)rv[3]) * sc[3] + sh[3];
          if (apply_bn){
            w0 = fmaxf(w0, 0.f); w1 = fmaxf(w1, 0.f);
            w2 = fmaxf(w2, 0.f); w3 = fmaxf(w3, 0.f);
          }
          a0 += w0 + tv[0];
          a1 += w1 + tv[1];
          a2 += w2 + tv[2];
          a3 += w3 + tv[3];
          rv = rvn; tv = tvn;
        }
      }
      s16x4 o;
      o[0] = (short)f2b(a0); o[1] = (short)f2b(a1);
      o[2] = (short)f2b(a2); o[3] = (short)f2b(a3);
      // swizzled As write: 8B store inside its 16B chunk
      int byteo = r * 512 + ((((lane >> 1) ^ (r & 7)) & 31) << 4) + ((lane & 1) << 3);
      *(s16x4*)(LB + byteo) = o;
    }
  }
  __syncthreads();   // As complete

  // ---- load A-fragments into registers (rows 0..31 shared by all waves) ----
  s16x8 af[2][8];
#pragma unroll
  for (int m = 0; m < 2; m++){
    int arow = m * 16 + lr;
#pragma unroll
    for (int ks = 0; ks < 8; ks++)
      af[m][ks] = *(const s16x8*)(LB + arow * 512 +
                                  ((ks * 64 + hi * 16) ^ ((arow & 7) << 4)));
  }
  __syncthreads();   // all frag loads done; LB becomes Ms[2][32][128]

  // ---- MLP ----
  f32x4 zero = {0.f, 0.f, 0.f, 0.f};
  f32x4 acc2[2][4];
#pragma unroll
  for (int m = 0; m < 2; m++)
#pragma unroll
    for (int n = 0; n < 4; n++) acc2[m][n] = zero;
  f32x4 acc1[2][2];

  auto G1 = [&](int cc){
#pragma unroll
    for (int m = 0; m < 2; m++)
#pragma unroll
      for (int n = 0; n < 2; n++) acc1[m][n] = zero;
#pragma unroll
    for (int ks = 0; ks < 8; ks++){
#pragma unroll
      for (int n = 0; n < 2; n++){
        int cb = cc * 8 + wc * 2 + n;
        s16x8 bf = *(const s16x8*)(Wp1 + (((size_t)cb * 8 + ks) * 64 + lane) * 8);
        acc1[0][n] = __builtin_amdgcn_mfma_f32_16x16x32_bf16(af[0][ks], bf, acc1[0][n], 0, 0, 0);
        acc1[1][n] = __builtin_amdgcn_mfma_f32_16x16x32_bf16(af[1][ks], bf, acc1[1][n], 0, 0, 0);
      }
    }
  };
  auto WMS = [&](int cc, int buf){
    char* ms = LB + buf * 8192;
#pragma unroll
    for (int n = 0; n < 2; n++){
      float bv = b2f(bias1[cc * 128 + wc * 32 + n * 16 + lr]);
      int c2 = (wc * 32 + n * 16 + lr) * 2;
#pragma unroll
      for (int m = 0; m < 2; m++)
#pragma unroll
        for (int r = 0; r < 4; r++){
          int mrow = m * 16 + hi * 4 + r;
          float v = fmaxf(acc1[m][n][r] + bv, 0.f);
          *(u16*)(ms + mrow * 256 + (c2 ^ ((mrow & 7) << 4))) = f2b(v);
        }
    }
  };

  G1(0);
  WMS(0, 0);
  __syncthreads();

#pragma unroll
  for (int c = 0; c < 4; c++){
    const char* ms = LB + (c & 1) * 8192;
#pragma unroll
    for (int ks = 0; ks < 4; ks++){
      s16x8 mf[2];
#pragma unroll
      for (int m = 0; m < 2; m++){
        int mrow = m * 16 + lr;
        mf[m] = *(const s16x8*)(ms + mrow * 256 +
                                ((ks * 64 + hi * 16) ^ ((mrow & 7) << 4)));
      }
#pragma unroll
      for (int n = 0; n < 4; n++){
        int cb2 = wc * 4 + n;
        s16x8 wf = *(const s16x8*)(Wp2 + (((size_t)cb2 * 16 + c * 4 + ks) * 64 + lane) * 8);
        acc2[0][n] = __builtin_amdgcn_mfma_f32_16x16x32_bf16(mf[0], wf, acc2[0][n], 0, 0, 0);
        acc2[1][n] = __builtin_amdgcn_mfma_f32_16x16x32_bf16(mf[1], wf, acc2[1][n], 0, 0, 0);
      }
    }
    if (c < 3){
      G1(c + 1);                    // reg-only A; overlaps with G2(c)
      WMS(c + 1, (c + 1) & 1);      // writes the buffer not being read
    }
    __syncthreads();
  }

  // ---- epilogue: bias2 -> LB bounce (full 16KB, rows*512) ----
#pragma unroll
  for (int n = 0; n < 4; n++){
    float bv = b2f(bias2[wc * 64 + n * 16 + lr]);
    int c2 = (wc * 64 + n * 16 + lr) * 2;
#pragma unroll
    for (int m = 0; m < 2; m++)
#pragma unroll
      for (int r = 0; r < 4; r++){
        int mrow = m * 16 + hi * 4 + r;
        *(u16*)(LB + mrow * 512 + (c2 ^ ((mrow & 7) << 4))) = f2b(acc2[m][n][r] + bv);
      }
  }
  __syncthreads();

  // ---- readback: coalesced 16B stores + BN partials ----
  float s[8], q[8];
#pragma unroll
  for (int e = 0; e < 8; e++){ s[e] = 0.f; q[e] = 0.f; }
  int sl = tid & 31;
#pragma unroll
  for (int p = 0; p < 4; p++){
    int r = p * 8 + (tid >> 5);
    s16x8 v = *(const s16x8*)(LB + r * 512 + ((sl << 4) ^ ((r & 7) << 4)));
    int gr = row0 + r;
    if (gr < M){
      *(s16x8*)(H + (size_t)gr * DD + sl * 8) = v;
      if (partial){
#pragma unroll
        for (int e = 0; e < 8; e++){
          float f = b2f((u16)v[e]);
          s[e] += f; q[e] += f * f;
        }
      }
    }
  }
  if (partial){
#pragma unroll
    for (int e = 0; e < 8; e++){
      s[e] += __shfl_xor(s[e], 32);
      q[e] += __shfl_xor(q[e], 32);
    }
    __syncthreads();                     // LB reads done; reuse for reduction
    float* redS = (float*)LB;            // 4x256 f32
    float* redQ = redS + 4 * 256;        // 4x256 f32 (8KB total)
    if (lane < 32){
#pragma unroll
      for (int e = 0; e < 8; e++){
        redS[wave * 256 + sl * 8 + e] = s[e];
        redQ[wave * 256 + sl * 8 + e] = q[e];
      }
    }
    __syncthreads();
    float a = 0.f, b = 0.f;
#pragma unroll
    for (int w = 0; w < 4; w++){ a += redS[w * 256 + tid]; b += redQ[w * 256 + tid]; }
    partial[(size_t)blockIdx.x * DD + tid] = a;
    partial[(size_t)(npart + blockIdx.x) * DD + tid] = b;
  }
}

// ---------------- BN reduce: sums[which][j] = sum over npart partials ----
__global__ void bn_reduce(const float* __restrict__ partial, float* __restrict__ sums,
                          int npart){
  int b = blockIdx.x, which = b >> 3, jg = b & 7;  // grid = 16
  int t = threadIdx.x;
  int j = jg * 32 + (t >> 3);
  int li = t & 7;
  float s = 0.f;
  for (int i = li; i < npart; i += 8)
    s += partial[(size_t)(which * npart + i) * DD + j];
  s += __shfl_xor(s, 1); s += __shfl_xor(s, 2); s += __shfl_xor(s, 4);
  if (li == 0) sums[which * DD + j] = s;
}

// ---------------- host ----------------
extern "C" void kernel_launch(void* const* d_in, const int* in_sizes, int n_in,
                              void* d_out, int out_size, void* d_ws, size_t ws_size,
                              hipStream_t stream){
  (void)n_in; (void)out_size; (void)ws_size;
  const int* x    = (const int*)d_in[0];
  const int* ei   = (const int*)d_in[1];
  const int* ea   = (const int*)d_in[2];
  const void* xe1 = d_in[3];
  const void* xe2 = d_in[4];
  const void* ee1 = d_in[5];
  const void* ee2 = d_in[6];
  const void* W1  = d_in[7];
  const void* b1  = d_in[8];
  const void* W2  = d_in[9];
  const void* b2  = d_in[10];
  const void* gam = d_in[11];
  const void* bet = d_in[12];

  int N = in_sizes[0] / 2;
  int E = in_sizes[1] / 2;
  int NB = (N + 1023) / 1024;
  const int L = 5;
  int nblk = (N + 31) / 32;        // fused-layer blocks (32 rows each)
  int npart = nblk;                // BN partials (one per block)

  // manual workspace carve (256B aligned)
  char* base = (char*)d_ws;
  size_t off = 0;
  u32* flag    = (u32*)(base + off);   off += 256;
  float* TBL   = (float*)(base + off); off += ((size_t)L * 18 * DD * 4 + 255) & ~(size_t)255;
  int* counts  = (int*)(base + off);   off += ((size_t)N * 4 + 255) & ~(size_t)255;
  int* offsets = (int*)(base + off);   off += ((size_t)N * 4 + 255) & ~(size_t)255;
  int* cursor  = (int*)(base + off);   off += ((size_t)N * 4 + 255) & ~(size_t)255;
  int* bsum    = (int*)(base + off);   off += ((size_t)NB * 4 + 255) & ~(size_t)255;
  int* payload = (int*)(base + off);   off += ((size_t)E * 4 + 255) & ~(size_t)255;
  float* part  = (float*)(base + off); off += ((size_t)2 * npart * DD * 4 + 255) & ~(size_t)255;
  float* sums  = (float*)(base + off); off += ((size_t)2 * DD * 4 + 255) & ~(size_t)255;
  // bf16 working copies of float inputs
  u16* wx1  = (u16*)(base + off); off += ((size_t)120 * DD * 2 + 255) & ~(size_t)255;
  u16* wx2  = (u16*)(base + off); off += ((size_t)3 * DD * 2 + 255) & ~(size_t)255;
  u16* wee1 = (u16*)(base + off); off += ((size_t)L * 6 * DD * 2 + 255) & ~(size_t)255;
  u16* wee2 = (u16*)(base + off); off += ((size_t)L * 3 * DD * 2 + 255) & ~(size_t)255;
  u16* wW1  = (u16*)(base + off); off += ((size_t)L * DD * 2 * DD * 2 + 255) & ~(size_t)255;
  u16* wb1  = (u16*)(base + off); off += ((size_t)L * 2 * DD * 2 + 255) & ~(size_t)255;
  u16* wW2  = (u16*)(base + off); off += ((size_t)L * 2 * DD * DD * 2 + 255) & ~(size_t)255;
  u16* wb2  = (u16*)(base + off); off += ((size_t)L * DD * 2 + 255) & ~(size_t)255;
  u16* wgam = (u16*)(base + off); off += ((size_t)(L - 1) * DD * 2 + 255) & ~(size_t)255;
  u16* wbet = (u16*)(base + off); off += ((size_t)(L - 1) * DD * 2 + 255) & ~(size_t)255;
  // packed MFMA B fragments
  u16* Wp1  = (u16*)(base + off); off += ((size_t)L * DD * 2 * DD * 2 + 255) & ~(size_t)255;
  u16* Wp2  = (u16*)(base + off); off += ((size_t)L * 2 * DD * DD * 2 + 255) & ~(size_t)255;
  // ping-pong feature buffers (bf16)
  u16* featA = (u16*)(base + off); off += ((size_t)N * DD * 2 + 255) & ~(size_t)255;
  u16* featB = (u16*)(base + off); off += ((size_t)N * DD * 2 + 255) & ~(size_t)255;

  // dtype probe + input conversion to bf16 working copies
  probe_dtype<<<1, 64, 0, stream>>>((const u32*)xe1, flag);
  cvt_in<<<(120 * DD + 255) / 256, 256, 0, stream>>>(xe1, wx1, 120 * DD, flag);
  cvt_in<<<(3 * DD + 255) / 256, 256, 0, stream>>>(xe2, wx2, 3 * DD, flag);
  cvt_in<<<(L * 6 * DD + 255) / 256, 256, 0, stream>>>(ee1, wee1, L * 6 * DD, flag);
  cvt_in<<<(L * 3 * DD + 255) / 256, 256, 0, stream>>>(ee2, wee2, L * 3 * DD, flag);
  cvt_in<<<(L * DD * 2 * DD + 255) / 256, 256, 0, stream>>>(W1, wW1, L * DD * 2 * DD, flag);
  cvt_in<<<(L * 2 * DD + 255) / 256, 256, 0, stream>>>(b1, wb1, L * 2 * DD, flag);
  cvt_in<<<(L * 2 * DD * DD + 255) / 256, 256, 0, stream>>>(W2, wW2, L * 2 * DD * DD, flag);
  cvt_in<<<(L * DD + 255) / 256, 256, 0, stream>>>(b2, wb2, L * DD, flag);
  cvt_in<<<((L - 1) * DD + 255) / 256, 256, 0, stream>>>(gam, wgam, (L - 1) * DD, flag);
  cvt_in<<<((L - 1) * DD + 255) / 256, 256, 0, stream>>>(bet, wbet, (L - 1) * DD, flag);

  // one-time per call: tables, packed weights (batched), CSR
  build_table<<<90, 256, 0, stream>>>(wee1, wee2, TBL);
  pack_B<<<dim3(64, L), 256, 0, stream>>>(wW1, Wp1, DD, 2 * DD);
  pack_B<<<dim3(64, L), 256, 0, stream>>>(wW2, Wp2, 2 * DD, DD);
  zero_int<<<(N + 255) / 256, 256, 0, stream>>>(counts, N);
  hist_kernel<<<(E + 255) / 256, 256, 0, stream>>>(ei + E, counts, E);
  scan_sums<<<NB, 256, 0, stream>>>(counts, bsum, N);
  scan_top<<<1, 64, 0, stream>>>(bsum, NB);
  scan_block<<<NB, 256, 0, stream>>>(counts, bsum, offsets, cursor, N);
  fill_csr<<<(E + 255) / 256, 256, 0, stream>>>(ei, ea, cursor, payload, E);

  // initial node features
  node_embed<<<(N * DD + 255) / 256, 256, 0, stream>>>(x, wx1, wx2, featA, N);

  float invN = 1.0f / (float)N;
  u16* fin = featA;
  u16* fout = featB;

  for (int l = 0; l < L; l++){
    layer_fused<<<nblk, 256, 0, stream>>>(
        fin, TBL + (size_t)l * 18 * DD, offsets, counts, payload,
        Wp1 + (size_t)l * DD * 2 * DD, wb1 + (size_t)l * 2 * DD,
        Wp2 + (size_t)l * 2 * DD * DD, wb2 + (size_t)l * DD,
        fout, (l < L - 1) ? part : (float*)nullptr, npart, N,
        sums, wgam + (size_t)(l > 0 ? l - 1 : 0) * DD,
        wbet + (size_t)(l > 0 ? l - 1 : 0) * DD, invN, l > 0 ? 1 : 0);

    if (l < L - 1){
      bn_reduce<<<16, 256, 0, stream>>>(part, sums, npart);
    }
    u16* t = fin; fin = fout; fout = t;
  }

  // final h is in fin (after swap); write to d_out in the proper dtype
  store_out<<<(N * DD + 255) / 256, 256, 0, stream>>>(fin, d_out, N * DD, flag);
}

// Round 8
// 1603.225 us; speedup vs baseline: 1.3630x; 1.3630x over previous
//
#include <hip/hip_runtime.h>

typedef unsigned short u16;
typedef unsigned int u32;

#define DD 256

typedef short  s16x8 __attribute__((ext_vector_type(8)));
typedef short  s16x4 __attribute__((ext_vector_type(4)));
typedef float  f32x4 __attribute__((ext_vector_type(4)));

__device__ __forceinline__ float b2f(u16 u){
  union { u32 i; float f; } c; c.i = ((u32)u) << 16; return c.f;
}
// round-to-nearest-even f32 -> bf16 (finite inputs)
__device__ __forceinline__ u16 f2b(float f){
  union { float f; u32 i; } c; c.f = f;
  u32 b = c.i + 0x7FFFu + ((c.i >> 16) & 1u);
  return (u16)(b >> 16);
}

// keep the harness's expected symbol name alive
__global__ void NodeEncoder_72971494359603_kernel(){}

// ---------------- dtype probe ----------------
__global__ void probe_dtype(const u32* w, u32* flag){
  if (threadIdx.x == 0 && blockIdx.x == 0){
    int cnt = 0;
    for (int i = 0; i < 256; i++){
      u32 low = w[i] & 0xFFFFu;
      u32 e = (low >> 7) & 0xFFu;
      if (e >= 0x60u && e <= 0x7Eu) cnt++;
    }
    *flag = (cnt >= 192) ? 1u : 0u;
  }
}

__global__ void cvt_in(const void* src, u16* dst, int n, const u32* flag){
  int i = blockIdx.x * 256 + threadIdx.x;
  if (i < n){
    if (*flag){
      dst[i] = ((const u16*)src)[i];
    } else {
      dst[i] = f2b(((const float*)src)[i]);
    }
  }
}

__global__ void store_out(const u16* h, void* dout, int n, const u32* flag){
  int i = blockIdx.x * 256 + threadIdx.x;
  if (i < n){
    if (*flag){
      ((u16*)dout)[i] = h[i];
    } else {
      ((float*)dout)[i] = b2f(h[i]);
    }
  }
}

// ---------------- utility ----------------
__global__ void zero_int(int* p, int n){
  int i = blockIdx.x * 256 + threadIdx.x;
  if (i < n) p[i] = 0;
}

// TBL[(l*18 + a*3 + b)*256 + j] = ee1[l][a][j] + ee2[l][b][j]   (f32)
__global__ void build_table(const u16* ee1, const u16* ee2, float* TBL){
  int b = blockIdx.x;               // 0..89
  int l = b / 18, c = b % 18, a = c / 3, bb = c % 3;
  int j = threadIdx.x;
  TBL[b * DD + j] = b2f(ee1[(l * 6 + a) * DD + j]) + b2f(ee2[(l * 3 + bb) * DD + j]);
}

// ---------------- CSR build ----------------
__global__ void hist_kernel(const int* dst, int* counts, int E){
  int e = blockIdx.x * 256 + threadIdx.x;
  if (e < E) atomicAdd(&counts[dst[e]], 1);
}

__global__ void scan_sums(const int* counts, int* bsum, int N){
  __shared__ int red[256];
  int tid = threadIdx.x;
  int base = blockIdx.x * 1024;
  int s = 0;
  for (int i = tid; i < 1024; i += 256){
    int g = base + i;
    if (g < N) s += counts[g];
  }
  red[tid] = s;
  __syncthreads();
  for (int off = 128; off > 0; off >>= 1){
    if (tid < off) red[tid] += red[tid + off];
    __syncthreads();
  }
  if (tid == 0) bsum[blockIdx.x] = red[0];
}

__global__ void scan_top(int* bsum, int nb){
  if (threadIdx.x == 0 && blockIdx.x == 0){
    int acc = 0;
    for (int i = 0; i < nb; i++){ int t = bsum[i]; bsum[i] = acc; acc += t; }
  }
}

__global__ void scan_block(const int* counts, const int* bsum,
                           int* offsets, int* cursor, int N){
  __shared__ int tsum[256];
  int b = blockIdx.x;
  int tid = threadIdx.x;
  int base = b * 1024;
  int v0, v1, v2, v3;
  int g = base + tid * 4;
  v0 = (g + 0 < N) ? counts[g + 0] : 0;
  v1 = (g + 1 < N) ? counts[g + 1] : 0;
  v2 = (g + 2 < N) ? counts[g + 2] : 0;
  v3 = (g + 3 < N) ? counts[g + 3] : 0;
  tsum[tid] = v0 + v1 + v2 + v3;
  __syncthreads();
  for (int off = 1; off < 256; off <<= 1){
    int t = (tid >= off) ? tsum[tid - off] : 0;
    __syncthreads();
    tsum[tid] += t;
    __syncthreads();
  }
  int excl = (tid == 0 ? 0 : tsum[tid - 1]) + bsum[b];
  if (g + 0 < N){ offsets[g + 0] = excl; cursor[g + 0] = excl; } excl += v0;
  if (g + 1 < N){ offsets[g + 1] = excl; cursor[g + 1] = excl; } excl += v1;
  if (g + 2 < N){ offsets[g + 2] = excl; cursor[g + 2] = excl; } excl += v2;
  if (g + 3 < N){ offsets[g + 3] = excl; cursor[g + 3] = excl; }
}

// payload[pos] = src | ((ea0*3+ea1) << 17)
__global__ void fill_csr(const int* ei, const int* ea, int* cursor,
                         int* payload, int E){
  int e = blockIdx.x * 256 + threadIdx.x;
  if (e < E){
    int d = ei[E + e];
    int pos = atomicAdd(&cursor[d], 1);
    int a = ea[2 * e], bb = ea[2 * e + 1];
    payload[pos] = ei[e] | ((a * 3 + bb) << 17);
  }
}

// ---------------- node embedding ----------------
__global__ void node_embed(const int* x, const u16* xe1, const u16* xe2,
                           u16* out, int N){
  int idx = blockIdx.x * 256 + threadIdx.x;
  if (idx < N * DD){
    int n = idx >> 8, j = idx & 255;
    int x0 = x[2 * n], x1 = x[2 * n + 1];
    out[idx] = f2b(b2f(xe1[x0 * DD + j]) + b2f(xe2[x1 * DD + j]));
  }
}

// ---------------- B packing for MFMA fragments (batched over layers) ----
// Wp chunk layout: frag = (cblk*(K/32) + ksub); lane l of frag holds
// W[ksub*32 + (l>>4)*8 + e][cblk*16 + (l&15)], e=0..7.
__global__ void pack_B(const u16* __restrict__ W0, u16* __restrict__ Wp0, int K, int Nc){
  const u16* W = W0 + (size_t)blockIdx.y * K * Nc;
  u16* Wp = Wp0 + (size_t)blockIdx.y * K * Nc;
  int idx = blockIdx.x * 256 + threadIdx.x;
  int lane = idx & 63;
  int t = idx >> 6;
  int nk = K >> 5;
  int ksub = t % nk, cblk = t / nk;
  if (cblk >= (Nc >> 4)) return;
  int col = cblk * 16 + (lane & 15);
  int krow = ksub * 32 + (lane >> 4) * 8;
  u16* dst = Wp + (size_t)idx * 8;
#pragma unroll
  for (int e = 0; e < 8; e++)
    dst[e] = W[(size_t)(krow + e) * Nc + col];
}

// ---------------- fused layer: gather(+BN+relu) -> MLP -> BN partials ----
// Round-6 structure (the verified 232us/layer config) + batch-4 edge ILP.
// One block = 64 nodes, 512 threads = 8 waves.
// Phase 0: gather CSR sums into swizzled As (TBL staged in Ms overlay);
//   per row, up to 4 edge loads issued concurrently (latency overlap).
// Then: pipelined MLP (Ms double-buffered, 1 barrier/chunk), coalesced H
//   stores via As bounce, fused BN partial sums.
__global__ __launch_bounds__(512, 4)
void layer_fused(const u16* __restrict__ feat, const float* __restrict__ TBL,
                 const int* __restrict__ offsets, const int* __restrict__ counts,
                 const int* __restrict__ payload,
                 const u16* __restrict__ Wp1, const u16* __restrict__ bias1,
                 const u16* __restrict__ Wp2, const u16* __restrict__ bias2,
                 u16* __restrict__ H, float* __restrict__ partial, int npart, int M,
                 const float* __restrict__ sums, const u16* __restrict__ gamma,
                 const u16* __restrict__ beta, float invN, int apply_bn){
  __shared__ __align__(16) u16 As[64 * 256];     // 32 KB
  __shared__ __align__(16) u16 Ms[2][64 * 128];  // 2 x 16 KB
  float* T = (float*)Ms;                         // 18 KB overlay, dead after gather
  int tid = threadIdx.x, lane = tid & 63, wave = tid >> 6;
  int wr = wave >> 2, wc = wave & 3;             // 2 x 4 wave grid (MLP phases)
  int row0 = blockIdx.x * 64;
  int lr = lane & 15, hi = lane >> 4;

  // ---- stage TBL into Ms overlay ----
  for (int i = tid; i < 18 * DD; i += 512) T[i] = TBL[i];
  __syncthreads();

  // ---- phase 0: gather into As (wave handles rows wave*8 .. wave*8+7) ----
  {
    int c4 = lane * 4;
    float sc[4], sh[4];
    if (apply_bn){
#pragma unroll
      for (int e = 0; e < 4; e++){
        int j = c4 + e;
        float mean = sums[j] * invN;
        float var = sums[DD + j] * invN - mean * mean;
        if (var < 0.f) var = 0.f;
        float scl = rsqrtf(var + 1e-5f) * b2f(gamma[j]);
        sc[e] = scl; sh[e] = b2f(beta[j]) - mean * scl;
      }
    } else {
#pragma unroll
      for (int e = 0; e < 4; e++){ sc[e] = 1.f; sh[e] = 0.f; }
    }
    for (int u = 0; u < 8; u++){
      int r = wave * 8 + u;
      int n = row0 + r; if (n > M - 1) n = M - 1;   // tail rows duplicate (never stored)
      s16x4 sv = *(const s16x4*)(feat + (size_t)n * DD + c4);
      f32x4 tb = *(const f32x4*)(T + 12 * DD + c4);  // self-loop (4,0) -> idx 12
      float v0 = b2f((u16)sv[0]) * sc[0] + sh[0];
      float v1 = b2f((u16)sv[1]) * sc[1] + sh[1];
      float v2 = b2f((u16)sv[2]) * sc[2] + sh[2];
      float v3 = b2f((u16)sv[3]) * sc[3] + sh[3];
      if (apply_bn){
        v0 = fmaxf(v0, 0.f); v1 = fmaxf(v1, 0.f);
        v2 = fmaxf(v2, 0.f); v3 = fmaxf(v3, 0.f);
      }
      float a0 = v0 + tb[0], a1 = v1 + tb[1], a2 = v2 + tb[2], a3 = v3 + tb[3];
      int e0 = offsets[n], eend = e0 + counts[n];
      // batch-4 edge ILP: issue all <=4 loads before consuming
      for (int e = e0; e < eend; e += 4){
        int nb = eend - e; if (nb > 4) nb = 4;
        int pls[4]; s16x4 rvs[4]; f32x4 tvs[4];
#pragma unroll
        for (int i = 0; i < 4; i++)
          if (i < nb) pls[i] = payload[e + i];
#pragma unroll
        for (int i = 0; i < 4; i++)
          if (i < nb){
            rvs[i] = *(const s16x4*)(feat + (size_t)(pls[i] & 0x1FFFF) * DD + c4);
            tvs[i] = *(const f32x4*)(T + (pls[i] >> 17) * DD + c4);
          }
#pragma unroll
        for (int i = 0; i < 4; i++)
          if (i < nb){
            float w0 = b2f((u16)rvs[i][0]) * sc[0] + sh[0];
            float w1 = b2f((u16)rvs[i][1]) * sc[1] + sh[1];
            float w2 = b2f((u16)rvs[i][2]) * sc[2] + sh[2];
            float w3 = b2f((u16)rvs[i][3]) * sc[3] + sh[3];
            if (apply_bn){
              w0 = fmaxf(w0, 0.f); w1 = fmaxf(w1, 0.f);
              w2 = fmaxf(w2, 0.f); w3 = fmaxf(w3, 0.f);
            }
            a0 += w0 + tvs[i][0];
            a1 += w1 + tvs[i][1];
            a2 += w2 + tvs[i][2];
            a3 += w3 + tvs[i][3];
          }
      }
      s16x4 o;
      o[0] = (short)f2b(a0); o[1] = (short)f2b(a1);
      o[2] = (short)f2b(a2); o[3] = (short)f2b(a3);
      // swizzled As write: 8B store inside its 16B chunk
      int byteo = r * 512 + ((((lane >> 1) ^ (r & 7)) & 31) << 4) + ((lane & 1) << 3);
      *(s16x4*)((char*)As + byteo) = o;
    }
  }
  __syncthreads();   // As complete; T dead

  // ---- MLP phases ----
  f32x4 zero = {0.f, 0.f, 0.f, 0.f};
  f32x4 acc2[2][4];
#pragma unroll
  for (int m = 0; m < 2; m++)
#pragma unroll
    for (int n = 0; n < 4; n++) acc2[m][n] = zero;
  f32x4 acc1[2][2];

  auto G1 = [&](int cc){
#pragma unroll
    for (int m = 0; m < 2; m++)
#pragma unroll
      for (int n = 0; n < 2; n++) acc1[m][n] = zero;
#pragma unroll
    for (int ks = 0; ks < 8; ks++){
      s16x8 af[2];
#pragma unroll
      for (int m = 0; m < 2; m++){
        int arow = wr * 32 + m * 16 + lr;
        af[m] = *(const s16x8*)((const char*)As + arow * 512 +
                                ((ks * 64 + hi * 16) ^ ((arow & 7) << 4)));
      }
#pragma unroll
      for (int n = 0; n < 2; n++){
        int cb = cc * 8 + wc * 2 + n;
        s16x8 bf = *(const s16x8*)(Wp1 + (((size_t)cb * 8 + ks) * 64 + lane) * 8);
        acc1[0][n] = __builtin_amdgcn_mfma_f32_16x16x32_bf16(af[0], bf, acc1[0][n], 0, 0, 0);
        acc1[1][n] = __builtin_amdgcn_mfma_f32_16x16x32_bf16(af[1], bf, acc1[1][n], 0, 0, 0);
      }
    }
  };
  auto WMS = [&](int cc, int buf){
    char* ms = (char*)Ms[buf];
#pragma unroll
    for (int n = 0; n < 2; n++){
      float bv = b2f(bias1[cc * 128 + wc * 32 + n * 16 + lr]);
      int c2 = (wc * 32 + n * 16 + lr) * 2;
#pragma unroll
      for (int m = 0; m < 2; m++)
#pragma unroll
        for (int r = 0; r < 4; r++){
          int mrow = wr * 32 + m * 16 + hi * 4 + r;
          float v = fmaxf(acc1[m][n][r] + bv, 0.f);
          *(u16*)(ms + mrow * 256 + (c2 ^ ((mrow & 7) << 4))) = f2b(v);
        }
    }
  };

  G1(0);
  WMS(0, 0);
  __syncthreads();

#pragma unroll
  for (int c = 0; c < 4; c++){
    const char* ms = (const char*)Ms[c & 1];
#pragma unroll
    for (int ks = 0; ks < 4; ks++){
      s16x8 mf[2];
#pragma unroll
      for (int m = 0; m < 2; m++){
        int mrow = wr * 32 + m * 16 + lr;
        mf[m] = *(const s16x8*)(ms + mrow * 256 +
                                ((ks * 64 + hi * 16) ^ ((mrow & 7) << 4)));
      }
#pragma unroll
      for (int n = 0; n < 4; n++){
        int cb2 = wc * 4 + n;
        s16x8 wf = *(const s16x8*)(Wp2 + (((size_t)cb2 * 16 + c * 4 + ks) * 64 + lane) * 8);
        acc2[0][n] = __builtin_amdgcn_mfma_f32_16x16x32_bf16(mf[0], wf, acc2[0][n], 0, 0, 0);
        acc2[1][n] = __builtin_amdgcn_mfma_f32_16x16x32_bf16(mf[1], wf, acc2[1][n], 0, 0, 0);
      }
    }
    if (c < 3){
      G1(c + 1);                    // overlaps with G2(c) in this region
      WMS(c + 1, (c + 1) & 1);      // writes the buffer not being read
      __syncthreads();
    }
  }

  // ---- epilogue: bias2 -> As bounce ----
#pragma unroll
  for (int n = 0; n < 4; n++){
    float bv = b2f(bias2[wc * 64 + n * 16 + lr]);
    int c2 = (wc * 64 + n * 16 + lr) * 2;
#pragma unroll
    for (int m = 0; m < 2; m++)
#pragma unroll
      for (int r = 0; r < 4; r++){
        int mrow = wr * 32 + m * 16 + hi * 4 + r;
        *(u16*)((char*)As + mrow * 512 + (c2 ^ ((mrow & 7) << 4))) = f2b(acc2[m][n][r] + bv);
      }
  }
  __syncthreads();

  // ---- readback: coalesced 16B stores + BN partials ----
  float s[8], q[8];
#pragma unroll
  for (int e = 0; e < 8; e++){ s[e] = 0.f; q[e] = 0.f; }
  int sl = tid & 31;
#pragma unroll
  for (int p = 0; p < 4; p++){
    int r = p * 16 + (tid >> 5);
    s16x8 v = *(const s16x8*)((const char*)As + r * 512 + ((sl << 4) ^ ((r & 7) << 4)));
    int gr = row0 + r;
    if (gr < M){
      *(s16x8*)(H + (size_t)gr * DD + sl * 8) = v;
      if (partial){
#pragma unroll
        for (int e = 0; e < 8; e++){
          float f = b2f((u16)v[e]);
          s[e] += f; q[e] += f * f;
        }
      }
    }
  }
  if (partial){
#pragma unroll
    for (int e = 0; e < 8; e++){
      s[e] += __shfl_xor(s[e], 32);
      q[e] += __shfl_xor(q[e], 32);
    }
    float* redS = (float*)Ms;            // 8x256 f32
    float* redQ = redS + 8 * 256;        // 8x256 f32
    if (lane < 32){
#pragma unroll
      for (int e = 0; e < 8; e++){
        redS[wave * 256 + sl * 8 + e] = s[e];
        redQ[wave * 256 + sl * 8 + e] = q[e];
      }
    }
    __syncthreads();
    if (tid < 256){
      float a = 0.f, b = 0.f;
#pragma unroll
      for (int w = 0; w < 8; w++){ a += redS[w * 256 + tid]; b += redQ[w * 256 + tid]; }
      partial[(size_t)blockIdx.x * DD + tid] = a;
      partial[(size_t)(npart + blockIdx.x) * DD + tid] = b;
    }
  }
}

// ---------------- BN reduce: sums[which][j] = sum over npart partials ----
__global__ void bn_reduce(const float* __restrict__ partial, float* __restrict__ sums,
                          int npart){
  int b = blockIdx.x, which = b >> 3, jg = b & 7;  // grid = 16
  int t = threadIdx.x;
  int j = jg * 32 + (t >> 3);
  int li = t & 7;
  float s = 0.f;
  for (int i = li; i < npart; i += 8)
    s += partial[(size_t)(which * npart + i) * DD + j];
  s += __shfl_xor(s, 1); s += __shfl_xor(s, 2); s += __shfl_xor(s, 4);
  if (li == 0) sums[which * DD + j] = s;
}

// ---------------- host ----------------
extern "C" void kernel_launch(void* const* d_in, const int* in_sizes, int n_in,
                              void* d_out, int out_size, void* d_ws, size_t ws_size,
                              hipStream_t stream){
  (void)n_in; (void)out_size; (void)ws_size;
  const int* x    = (const int*)d_in[0];
  const int* ei   = (const int*)d_in[1];
  const int* ea   = (const int*)d_in[2];
  const void* xe1 = d_in[3];
  const void* xe2 = d_in[4];
  const void* ee1 = d_in[5];
  const void* ee2 = d_in[6];
  const void* W1  = d_in[7];
  const void* b1  = d_in[8];
  const void* W2  = d_in[9];
  const void* b2  = d_in[10];
  const void* gam = d_in[11];
  const void* bet = d_in[12];

  int N = in_sizes[0] / 2;
  int E = in_sizes[1] / 2;
  int NB = (N + 1023) / 1024;
  const int L = 5;
  int nblk = (N + 63) / 64;        // fused-layer blocks
  int npart = nblk;                // BN partials (one per block)

  // manual workspace carve (256B aligned)
  char* base = (char*)d_ws;
  size_t off = 0;
  u32* flag    = (u32*)(base + off);   off += 256;
  float* TBL   = (float*)(base + off); off += ((size_t)L * 18 * DD * 4 + 255) & ~(size_t)255;
  int* counts  = (int*)(base + off);   off += ((size_t)N * 4 + 255) & ~(size_t)255;
  int* offsets = (int*)(base + off);   off += ((size_t)N * 4 + 255) & ~(size_t)255;
  int* cursor  = (int*)(base + off);   off += ((size_t)N * 4 + 255) & ~(size_t)255;
  int* bsum    = (int*)(base + off);   off += ((size_t)NB * 4 + 255) & ~(size_t)255;
  int* payload = (int*)(base + off);   off += ((size_t)E * 4 + 255) & ~(size_t)255;
  float* part  = (float*)(base + off); off += ((size_t)2 * npart * DD * 4 + 255) & ~(size_t)255;
  float* sums  = (float*)(base + off); off += ((size_t)2 * DD * 4 + 255) & ~(size_t)255;
  // bf16 working copies of float inputs
  u16* wx1  = (u16*)(base + off); off += ((size_t)120 * DD * 2 + 255) & ~(size_t)255;
  u16* wx2  = (u16*)(base + off); off += ((size_t)3 * DD * 2 + 255) & ~(size_t)255;
  u16* wee1 = (u16*)(base + off); off += ((size_t)L * 6 * DD * 2 + 255) & ~(size_t)255;
  u16* wee2 = (u16*)(base + off); off += ((size_t)L * 3 * DD * 2 + 255) & ~(size_t)255;
  u16* wW1  = (u16*)(base + off); off += ((size_t)L * DD * 2 * DD * 2 + 255) & ~(size_t)255;
  u16* wb1  = (u16*)(base + off); off += ((size_t)L * 2 * DD * 2 + 255) & ~(size_t)255;
  u16* wW2  = (u16*)(base + off); off += ((size_t)L * 2 * DD * DD * 2 + 255) & ~(size_t)255;
  u16* wb2  = (u16*)(base + off); off += ((size_t)L * DD * 2 + 255) & ~(size_t)255;
  u16* wgam = (u16*)(base + off); off += ((size_t)(L - 1) * DD * 2 + 255) & ~(size_t)255;
  u16* wbet = (u16*)(base + off); off += ((size_t)(L - 1) * DD * 2 + 255) & ~(size_t)255;
  // packed MFMA B fragments
  u16* Wp1  = (u16*)(base + off); off += ((size_t)L * DD * 2 * DD * 2 + 255) & ~(size_t)255;
  u16* Wp2  = (u16*)(base + off); off += ((size_t)L * 2 * DD * DD * 2 + 255) & ~(size_t)255;
  // ping-pong feature buffers (bf16)
  u16* featA = (u16*)(base + off); off += ((size_t)N * DD * 2 + 255) & ~(size_t)255;
  u16* featB = (u16*)(base + off); off += ((size_t)N * DD * 2 + 255) & ~(size_t)255;

  // dtype probe + input conversion to bf16 working copies
  probe_dtype<<<1, 64, 0, stream>>>((const u32*)xe1, flag);
  cvt_in<<<(120 * DD + 255) / 256, 256, 0, stream>>>(xe1, wx1, 120 * DD, flag);
  cvt_in<<<(3 * DD + 255) / 256, 256, 0, stream>>>(xe2, wx2, 3 * DD, flag);
  cvt_in<<<(L * 6 * DD + 255) / 256, 256, 0, stream>>>(ee1, wee1, L * 6 * DD, flag);
  cvt_in<<<(L * 3 * DD + 255) / 256, 256, 0, stream>>>(ee2, wee2, L * 3 * DD, flag);
  cvt_in<<<(L * DD * 2 * DD + 255) / 256, 256, 0, stream>>>(W1, wW1, L * DD * 2 * DD, flag);
  cvt_in<<<(L * 2 * DD + 255) / 256, 256, 0, stream>>>(b1, wb1, L * 2 * DD, flag);
  cvt_in<<<(L * 2 * DD * DD + 255) / 256, 256, 0, stream>>>(W2, wW2, L * 2 * DD * DD, flag);
  cvt_in<<<(L * DD + 255) / 256, 256, 0, stream>>>(b2, wb2, L * DD, flag);
  cvt_in<<<((L - 1) * DD + 255) / 256, 256, 0, stream>>>(gam, wgam, (L - 1) * DD, flag);
  cvt_in<<<((L - 1) * DD + 255) / 256, 256, 0, stream>>>(bet, wbet, (L - 1) * DD, flag);

  // one-time per call: tables, packed weights (batched), CSR
  build_table<<<90, 256, 0, stream>>>(wee1, wee2, TBL);
  pack_B<<<dim3(64, L), 256, 0, stream>>>(wW1, Wp1, DD, 2 * DD);
  pack_B<<<dim3(64, L), 256, 0, stream>>>(wW2, Wp2, 2 * DD, DD);
  zero_int<<<(N + 255) / 256, 256, 0, stream>>>(counts, N);
  hist_kernel<<<(E + 255) / 256, 256, 0, stream>>>(ei + E, counts, E);
  scan_sums<<<NB, 256, 0, stream>>>(counts, bsum, N);
  scan_top<<<1, 64, 0, stream>>>(bsum, NB);
  scan_block<<<NB, 256, 0, stream>>>(counts, bsum, offsets, cursor, N);
  fill_csr<<<(E + 255) / 256, 256, 0, stream>>>(ei, ea, cursor, payload, E);

  // initial node features
  node_embed<<<(N * DD + 255) / 256, 256, 0, stream>>>(x, wx1, wx2, featA, N);

  float invN = 1.0f / (float)N;
  u16* fin = featA;
  u16* fout = featB;

  for (int l = 0; l < L; l++){
    layer_fused<<<nblk, 512, 0, stream>>>(
        fin, TBL + (size_t)l * 18 * DD, offsets, counts, payload,
        Wp1 + (size_t)l * DD * 2 * DD, wb1 + (size_t)l * 2 * DD,
        Wp2 + (size_t)l * 2 * DD * DD, wb2 + (size_t)l * DD,
        fout, (l < L - 1) ? part : (float*)nullptr, npart, N,
        sums, wgam + (size_t)(l > 0 ? l - 1 : 0) * DD,
        wbet + (size_t)(l > 0 ? l - 1 : 0) * DD, invN, l > 0 ? 1 : 0);

    if (l < L - 1){
      bn_reduce<<<16, 256, 0, stream>>>(part, sums, npart);
    }
    u16* t = fin; fin = fout; fout = t;
  }

  // final h is in fin (after swap); write to d_out in the proper dtype
  store_out<<<(N * DD + 255) / 256, 256, 0, stream>>>(fin, d_out, N * DD, flag);
}

// Round 9
// 1572.998 us; speedup vs baseline: 1.3892x; 1.0192x over previous
//
#include <hip/hip_runtime.h>

typedef unsigned short u16;
typedef unsigned int u32;

#define DD 256

typedef short  s16x8 __attribute__((ext_vector_type(8)));
typedef short  s16x4 __attribute__((ext_vector_type(4)));
typedef float  f32x4 __attribute__((ext_vector_type(4)));

__device__ __forceinline__ float b2f(u16 u){
  union { u32 i; float f; } c; c.i = ((u32)u) << 16; return c.f;
}
// round-to-nearest-even f32 -> bf16 (finite inputs)
__device__ __forceinline__ u16 f2b(float f){
  union { float f; u32 i; } c; c.f = f;
  u32 b = c.i + 0x7FFFu + ((c.i >> 16) & 1u);
  return (u16)(b >> 16);
}

// keep the harness's expected symbol name alive
__global__ void NodeEncoder_72971494359603_kernel(){}

// ---------------- dtype probe ----------------
__global__ void probe_dtype(const u32* w, u32* flag){
  if (threadIdx.x == 0 && blockIdx.x == 0){
    int cnt = 0;
    for (int i = 0; i < 256; i++){
      u32 low = w[i] & 0xFFFFu;
      u32 e = (low >> 7) & 0xFFu;
      if (e >= 0x60u && e <= 0x7Eu) cnt++;
    }
    *flag = (cnt >= 192) ? 1u : 0u;
  }
}

__global__ void cvt_in(const void* src, u16* dst, int n, const u32* flag){
  int i = blockIdx.x * 256 + threadIdx.x;
  if (i < n){
    if (*flag){
      dst[i] = ((const u16*)src)[i];
    } else {
      dst[i] = f2b(((const float*)src)[i]);
    }
  }
}

__global__ void store_out(const u16* h, void* dout, int n, const u32* flag){
  int i = blockIdx.x * 256 + threadIdx.x;
  if (i < n){
    if (*flag){
      ((u16*)dout)[i] = h[i];
    } else {
      ((float*)dout)[i] = b2f(h[i]);
    }
  }
}

// ---------------- utility ----------------
__global__ void zero_int(int* p, int n){
  int i = blockIdx.x * 256 + threadIdx.x;
  if (i < n) p[i] = 0;
}

// TBL16[(l*18 + a*3 + b)*256 + j] = bf16(ee1[l][a][j] + ee2[l][b][j])
__global__ void build_table(const u16* ee1, const u16* ee2, u16* TBL){
  int b = blockIdx.x;               // 0..89
  int l = b / 18, c = b % 18, a = c / 3, bb = c % 3;
  int j = threadIdx.x;
  TBL[b * DD + j] = f2b(b2f(ee1[(l * 6 + a) * DD + j]) + b2f(ee2[(l * 3 + bb) * DD + j]));
}

// ---------------- CSR build ----------------
__global__ void hist_kernel(const int* dst, int* counts, int E){
  int e = blockIdx.x * 256 + threadIdx.x;
  if (e < E) atomicAdd(&counts[dst[e]], 1);
}

__global__ void scan_sums(const int* counts, int* bsum, int N){
  __shared__ int red[256];
  int tid = threadIdx.x;
  int base = blockIdx.x * 1024;
  int s = 0;
  for (int i = tid; i < 1024; i += 256){
    int g = base + i;
    if (g < N) s += counts[g];
  }
  red[tid] = s;
  __syncthreads();
  for (int off = 128; off > 0; off >>= 1){
    if (tid < off) red[tid] += red[tid + off];
    __syncthreads();
  }
  if (tid == 0) bsum[blockIdx.x] = red[0];
}

__global__ void scan_top(int* bsum, int nb){
  if (threadIdx.x == 0 && blockIdx.x == 0){
    int acc = 0;
    for (int i = 0; i < nb; i++){ int t = bsum[i]; bsum[i] = acc; acc += t; }
  }
}

__global__ void scan_block(const int* counts, const int* bsum,
                           int* offsets, int* cursor, int N){
  __shared__ int tsum[256];
  int b = blockIdx.x;
  int tid = threadIdx.x;
  int base = b * 1024;
  int v0, v1, v2, v3;
  int g = base + tid * 4;
  v0 = (g + 0 < N) ? counts[g + 0] : 0;
  v1 = (g + 1 < N) ? counts[g + 1] : 0;
  v2 = (g + 2 < N) ? counts[g + 2] : 0;
  v3 = (g + 3 < N) ? counts[g + 3] : 0;
  tsum[tid] = v0 + v1 + v2 + v3;
  __syncthreads();
  for (int off = 1; off < 256; off <<= 1){
    int t = (tid >= off) ? tsum[tid - off] : 0;
    __syncthreads();
    tsum[tid] += t;
    __syncthreads();
  }
  int excl = (tid == 0 ? 0 : tsum[tid - 1]) + bsum[b];
  if (g + 0 < N){ offsets[g + 0] = excl; cursor[g + 0] = excl; } excl += v0;
  if (g + 1 < N){ offsets[g + 1] = excl; cursor[g + 1] = excl; } excl += v1;
  if (g + 2 < N){ offsets[g + 2] = excl; cursor[g + 2] = excl; } excl += v2;
  if (g + 3 < N){ offsets[g + 3] = excl; cursor[g + 3] = excl; }
}

// payload[pos] = src | ((ea0*3+ea1) << 17)
__global__ void fill_csr(const int* ei, const int* ea, int* cursor,
                         int* payload, int E){
  int e = blockIdx.x * 256 + threadIdx.x;
  if (e < E){
    int d = ei[E + e];
    int pos = atomicAdd(&cursor[d], 1);
    int a = ea[2 * e], bb = ea[2 * e + 1];
    payload[pos] = ei[e] | ((a * 3 + bb) << 17);
  }
}

// ---------------- node embedding ----------------
__global__ void node_embed(const int* x, const u16* xe1, const u16* xe2,
                           u16* out, int N){
  int idx = blockIdx.x * 256 + threadIdx.x;
  if (idx < N * DD){
    int n = idx >> 8, j = idx & 255;
    int x0 = x[2 * n], x1 = x[2 * n + 1];
    out[idx] = f2b(b2f(xe1[x0 * DD + j]) + b2f(xe2[x1 * DD + j]));
  }
}

// ---------------- B packing for MFMA fragments (batched over layers) ----
// Wp chunk layout: frag = (cblk*(K/32) + ksub); lane l of frag holds
// W[ksub*32 + (l>>4)*8 + e][cblk*16 + (l&15)], e=0..7.
__global__ void pack_B(const u16* __restrict__ W0, u16* __restrict__ Wp0, int K, int Nc){
  const u16* W = W0 + (size_t)blockIdx.y * K * Nc;
  u16* Wp = Wp0 + (size_t)blockIdx.y * K * Nc;
  int idx = blockIdx.x * 256 + threadIdx.x;
  int lane = idx & 63;
  int t = idx >> 6;
  int nk = K >> 5;
  int ksub = t % nk, cblk = t / nk;
  if (cblk >= (Nc >> 4)) return;
  int col = cblk * 16 + (lane & 15);
  int krow = ksub * 32 + (lane >> 4) * 8;
  u16* dst = Wp + (size_t)idx * 8;
#pragma unroll
  for (int e = 0; e < 8; e++)
    dst[e] = W[(size_t)(krow + e) * Nc + col];
}

// ---------------- fused layer: gather(+BN+relu) -> MLP -> BN partials ----
// 64 nodes/block, 512 threads = 8 waves. LDS = 48 KB -> 3 blocks/CU
// (24 waves, up from 2 blocks/16 waves at 64 KB). Edge table staged as
// bf16 (9 KB) in the Ms overlay. MLP: 8 chunks of 64 mid-cols, Ms
// double-buffered 2x8KB, 1 barrier/chunk, G2(c) || G1(c+1) pipeline.
__global__ __launch_bounds__(512, 6)
void layer_fused(const u16* __restrict__ feat, const u16* __restrict__ TBL,
                 const int* __restrict__ offsets, const int* __restrict__ counts,
                 const int* __restrict__ payload,
                 const u16* __restrict__ Wp1, const u16* __restrict__ bias1,
                 const u16* __restrict__ Wp2, const u16* __restrict__ bias2,
                 u16* __restrict__ H, float* __restrict__ partial, int npart, int M,
                 const float* __restrict__ sums, const u16* __restrict__ gamma,
                 const u16* __restrict__ beta, float invN, int apply_bn){
  __shared__ __align__(16) u16 As[64 * 256];    // 32 KB
  __shared__ __align__(16) u16 Ms[2][64 * 64];  // 2 x 8 KB
  u16* T = (u16*)Ms;                            // 9 KB bf16 table overlay
  int tid = threadIdx.x, lane = tid & 63, wave = tid >> 6;
  int wr = wave >> 2, wc = wave & 3;            // 2 x 4 wave grid (MLP phases)
  int row0 = blockIdx.x * 64;
  int lr = lane & 15, hi = lane >> 4;

  // ---- stage bf16 TBL into Ms overlay (9216 B) ----
  {
    u32* Tw = (u32*)T;
    const u32* Gw = (const u32*)TBL;
    for (int i = tid; i < 18 * DD / 2; i += 512) Tw[i] = Gw[i];
  }
  __syncthreads();

  // ---- phase 0: gather into As (wave handles rows wave*8 .. wave*8+7) ----
  {
    int c4 = lane * 4;
    float sc[4], sh[4];
    if (apply_bn){
#pragma unroll
      for (int e = 0; e < 4; e++){
        int j = c4 + e;
        float mean = sums[j] * invN;
        float var = sums[DD + j] * invN - mean * mean;
        if (var < 0.f) var = 0.f;
        float scl = rsqrtf(var + 1e-5f) * b2f(gamma[j]);
        sc[e] = scl; sh[e] = b2f(beta[j]) - mean * scl;
      }
    } else {
#pragma unroll
      for (int e = 0; e < 4; e++){ sc[e] = 1.f; sh[e] = 0.f; }
    }
    for (int u = 0; u < 8; u++){
      int r = wave * 8 + u;
      int n = row0 + r; if (n > M - 1) n = M - 1;   // tail rows duplicate (never stored)
      s16x4 sv = *(const s16x4*)(feat + (size_t)n * DD + c4);
      s16x4 tb = *(const s16x4*)(T + 12 * DD + c4);  // self-loop (4,0) -> idx 12
      float v0 = b2f((u16)sv[0]) * sc[0] + sh[0];
      float v1 = b2f((u16)sv[1]) * sc[1] + sh[1];
      float v2 = b2f((u16)sv[2]) * sc[2] + sh[2];
      float v3 = b2f((u16)sv[3]) * sc[3] + sh[3];
      if (apply_bn){
        v0 = fmaxf(v0, 0.f); v1 = fmaxf(v1, 0.f);
        v2 = fmaxf(v2, 0.f); v3 = fmaxf(v3, 0.f);
      }
      float a0 = v0 + b2f((u16)tb[0]);
      float a1 = v1 + b2f((u16)tb[1]);
      float a2 = v2 + b2f((u16)tb[2]);
      float a3 = v3 + b2f((u16)tb[3]);
      int e0 = offsets[n], eend = e0 + counts[n];
      // batch-4 edge ILP: issue all <=4 loads before consuming
      for (int e = e0; e < eend; e += 4){
        int nb = eend - e; if (nb > 4) nb = 4;
        int pls[4]; s16x4 rvs[4]; s16x4 tvs[4];
#pragma unroll
        for (int i = 0; i < 4; i++)
          if (i < nb) pls[i] = payload[e + i];
#pragma unroll
        for (int i = 0; i < 4; i++)
          if (i < nb){
            rvs[i] = *(const s16x4*)(feat + (size_t)(pls[i] & 0x1FFFF) * DD + c4);
            tvs[i] = *(const s16x4*)(T + (pls[i] >> 17) * DD + c4);
          }
#pragma unroll
        for (int i = 0; i < 4; i++)
          if (i < nb){
            float w0 = b2f((u16)rvs[i][0]) * sc[0] + sh[0];
            float w1 = b2f((u16)rvs[i][1]) * sc[1] + sh[1];
            float w2 = b2f((u16)rvs[i][2]) * sc[2] + sh[2];
            float w3 = b2f((u16)rvs[i][3]) * sc[3] + sh[3];
            if (apply_bn){
              w0 = fmaxf(w0, 0.f); w1 = fmaxf(w1, 0.f);
              w2 = fmaxf(w2, 0.f); w3 = fmaxf(w3, 0.f);
            }
            a0 += w0 + b2f((u16)tvs[i][0]);
            a1 += w1 + b2f((u16)tvs[i][1]);
            a2 += w2 + b2f((u16)tvs[i][2]);
            a3 += w3 + b2f((u16)tvs[i][3]);
          }
      }
      s16x4 o;
      o[0] = (short)f2b(a0); o[1] = (short)f2b(a1);
      o[2] = (short)f2b(a2); o[3] = (short)f2b(a3);
      // swizzled As write: 8B store inside its 16B chunk
      int byteo = r * 512 + ((((lane >> 1) ^ (r & 7)) & 31) << 4) + ((lane & 1) << 3);
      *(s16x4*)((char*)As + byteo) = o;
    }
  }
  __syncthreads();   // As complete; T dead

  // ---- MLP: 8 chunks of 64 mid-cols ----
  f32x4 zero = {0.f, 0.f, 0.f, 0.f};
  f32x4 acc2[2][4];
#pragma unroll
  for (int m = 0; m < 2; m++)
#pragma unroll
    for (int n = 0; n < 4; n++) acc2[m][n] = zero;
  f32x4 acc1[2];

  auto G1 = [&](int cc){
    acc1[0] = zero; acc1[1] = zero;
    int cb = cc * 4 + wc;               // mid col-block (of 32)
#pragma unroll
    for (int ks = 0; ks < 8; ks++){
      s16x8 af[2];
#pragma unroll
      for (int m = 0; m < 2; m++){
        int arow = wr * 32 + m * 16 + lr;
        af[m] = *(const s16x8*)((const char*)As + arow * 512 +
                                ((ks * 64 + hi * 16) ^ ((arow & 7) << 4)));
      }
      s16x8 bf = *(const s16x8*)(Wp1 + (((size_t)cb * 8 + ks) * 64 + lane) * 8);
      acc1[0] = __builtin_amdgcn_mfma_f32_16x16x32_bf16(af[0], bf, acc1[0], 0, 0, 0);
      acc1[1] = __builtin_amdgcn_mfma_f32_16x16x32_bf16(af[1], bf, acc1[1], 0, 0, 0);
    }
  };
  auto WMS = [&](int cc, int buf){
    char* ms = (char*)Ms[buf];
    float bv = b2f(bias1[cc * 64 + wc * 16 + lr]);
    int c2 = (wc * 16 + lr) * 2;
#pragma unroll
    for (int m = 0; m < 2; m++)
#pragma unroll
      for (int r = 0; r < 4; r++){
        int mrow = wr * 32 + m * 16 + hi * 4 + r;
        float v = fmaxf(acc1[m][r] + bv, 0.f);
        *(u16*)(ms + mrow * 128 + (c2 ^ ((mrow & 7) << 4))) = f2b(v);
      }
  };

  G1(0);
  WMS(0, 0);
  __syncthreads();

#pragma unroll
  for (int c = 0; c < 8; c++){
    const char* ms = (const char*)Ms[c & 1];
    // G2(c): k-slice [c*64, c*64+64), all 256 out cols
#pragma unroll
    for (int ks = 0; ks < 2; ks++){
      s16x8 mf[2];
#pragma unroll
      for (int m = 0; m < 2; m++){
        int mrow = wr * 32 + m * 16 + lr;
        mf[m] = *(const s16x8*)(ms + mrow * 128 +
                                ((ks * 64 + hi * 16) ^ ((mrow & 7) << 4)));
      }
#pragma unroll
      for (int n = 0; n < 4; n++){
        int cb2 = wc * 4 + n;
        s16x8 wf = *(const s16x8*)(Wp2 + (((size_t)cb2 * 16 + c * 2 + ks) * 64 + lane) * 8);
        acc2[0][n] = __builtin_amdgcn_mfma_f32_16x16x32_bf16(mf[0], wf, acc2[0][n], 0, 0, 0);
        acc2[1][n] = __builtin_amdgcn_mfma_f32_16x16x32_bf16(mf[1], wf, acc2[1][n], 0, 0, 0);
      }
    }
    if (c < 7){
      G1(c + 1);                    // overlaps with G2(c) in this region
      WMS(c + 1, (c + 1) & 1);      // writes the buffer not being read
      __syncthreads();
    }
  }

  // ---- epilogue: bias2 -> As bounce ----
#pragma unroll
  for (int n = 0; n < 4; n++){
    float bv = b2f(bias2[wc * 64 + n * 16 + lr]);
    int c2 = (wc * 64 + n * 16 + lr) * 2;
#pragma unroll
    for (int m = 0; m < 2; m++)
#pragma unroll
      for (int r = 0; r < 4; r++){
        int mrow = wr * 32 + m * 16 + hi * 4 + r;
        *(u16*)((char*)As + mrow * 512 + (c2 ^ ((mrow & 7) << 4))) = f2b(acc2[m][n][r] + bv);
      }
  }
  __syncthreads();

  // ---- readback: coalesced 16B stores + BN partials ----
  float s[8], q[8];
#pragma unroll
  for (int e = 0; e < 8; e++){ s[e] = 0.f; q[e] = 0.f; }
  int sl = tid & 31;
#pragma unroll
  for (int p = 0; p < 4; p++){
    int r = p * 16 + (tid >> 5);
    s16x8 v = *(const s16x8*)((const char*)As + r * 512 + ((sl << 4) ^ ((r & 7) << 4)));
    int gr = row0 + r;
    if (gr < M){
      *(s16x8*)(H + (size_t)gr * DD + sl * 8) = v;
      if (partial){
#pragma unroll
        for (int e = 0; e < 8; e++){
          float f = b2f((u16)v[e]);
          s[e] += f; q[e] += f * f;
        }
      }
    }
  }
  if (partial){
#pragma unroll
    for (int e = 0; e < 8; e++){
      s[e] += __shfl_xor(s[e], 32);
      q[e] += __shfl_xor(q[e], 32);
    }
    __syncthreads();                     // all As/Ms reads done
    float* redS = (float*)Ms;            // 8x256 f32 = 8 KB
    float* redQ = redS + 8 * 256;        // 8x256 f32 = 8 KB (fills 16 KB Ms)
    if (lane < 32){
#pragma unroll
      for (int e = 0; e < 8; e++){
        redS[wave * 256 + sl * 8 + e] = s[e];
        redQ[wave * 256 + sl * 8 + e] = q[e];
      }
    }
    __syncthreads();
    if (tid < 256){
      float a = 0.f, b = 0.f;
#pragma unroll
      for (int w = 0; w < 8; w++){ a += redS[w * 256 + tid]; b += redQ[w * 256 + tid]; }
      partial[(size_t)blockIdx.x * DD + tid] = a;
      partial[(size_t)(npart + blockIdx.x) * DD + tid] = b;
    }
  }
}

// ---------------- BN reduce: sums[which][j] = sum over npart partials ----
__global__ void bn_reduce(const float* __restrict__ partial, float* __restrict__ sums,
                          int npart){
  int b = blockIdx.x, which = b >> 3, jg = b & 7;  // grid = 16
  int t = threadIdx.x;
  int j = jg * 32 + (t >> 3);
  int li = t & 7;
  float s = 0.f;
  for (int i = li; i < npart; i += 8)
    s += partial[(size_t)(which * npart + i) * DD + j];
  s += __shfl_xor(s, 1); s += __shfl_xor(s, 2); s += __shfl_xor(s, 4);
  if (li == 0) sums[which * DD + j] = s;
}

// ---------------- host ----------------
extern "C" void kernel_launch(void* const* d_in, const int* in_sizes, int n_in,
                              void* d_out, int out_size, void* d_ws, size_t ws_size,
                              hipStream_t stream){
  (void)n_in; (void)out_size; (void)ws_size;
  const int* x    = (const int*)d_in[0];
  const int* ei   = (const int*)d_in[1];
  const int* ea   = (const int*)d_in[2];
  const void* xe1 = d_in[3];
  const void* xe2 = d_in[4];
  const void* ee1 = d_in[5];
  const void* ee2 = d_in[6];
  const void* W1  = d_in[7];
  const void* b1  = d_in[8];
  const void* W2  = d_in[9];
  const void* b2  = d_in[10];
  const void* gam = d_in[11];
  const void* bet = d_in[12];

  int N = in_sizes[0] / 2;
  int E = in_sizes[1] / 2;
  int NB = (N + 1023) / 1024;
  const int L = 5;
  int nblk = (N + 63) / 64;        // fused-layer blocks
  int npart = nblk;                // BN partials (one per block)

  // manual workspace carve (256B aligned)
  char* base = (char*)d_ws;
  size_t off = 0;
  u32* flag    = (u32*)(base + off);   off += 256;
  u16* TBL     = (u16*)(base + off);   off += ((size_t)L * 18 * DD * 2 + 255) & ~(size_t)255;
  int* counts  = (int*)(base + off);   off += ((size_t)N * 4 + 255) & ~(size_t)255;
  int* offsets = (int*)(base + off);   off += ((size_t)N * 4 + 255) & ~(size_t)255;
  int* cursor  = (int*)(base + off);   off += ((size_t)N * 4 + 255) & ~(size_t)255;
  int* bsum    = (int*)(base + off);   off += ((size_t)NB * 4 + 255) & ~(size_t)255;
  int* payload = (int*)(base + off);   off += ((size_t)E * 4 + 255) & ~(size_t)255;
  float* part  = (float*)(base + off); off += ((size_t)2 * npart * DD * 4 + 255) & ~(size_t)255;
  float* sums  = (float*)(base + off); off += ((size_t)2 * DD * 4 + 255) & ~(size_t)255;
  // bf16 working copies of float inputs
  u16* wx1  = (u16*)(base + off); off += ((size_t)120 * DD * 2 + 255) & ~(size_t)255;
  u16* wx2  = (u16*)(base + off); off += ((size_t)3 * DD * 2 + 255) & ~(size_t)255;
  u16* wee1 = (u16*)(base + off); off += ((size_t)L * 6 * DD * 2 + 255) & ~(size_t)255;
  u16* wee2 = (u16*)(base + off); off += ((size_t)L * 3 * DD * 2 + 255) & ~(size_t)255;
  u16* wW1  = (u16*)(base + off); off += ((size_t)L * DD * 2 * DD * 2 + 255) & ~(size_t)255;
  u16* wb1  = (u16*)(base + off); off += ((size_t)L * 2 * DD * 2 + 255) & ~(size_t)255;
  u16* wW2  = (u16*)(base + off); off += ((size_t)L * 2 * DD * DD * 2 + 255) & ~(size_t)255;
  u16* wb2  = (u16*)(base + off); off += ((size_t)L * DD * 2 + 255) & ~(size_t)255;
  u16* wgam = (u16*)(base + off); off += ((size_t)(L - 1) * DD * 2 + 255) & ~(size_t)255;
  u16* wbet = (u16*)(base + off); off += ((size_t)(L - 1) * DD * 2 + 255) & ~(size_t)255;
  // packed MFMA B fragments
  u16* Wp1  = (u16*)(base + off); off += ((size_t)L * DD * 2 * DD * 2 + 255) & ~(size_t)255;
  u16* Wp2  = (u16*)(base + off); off += ((size_t)L * 2 * DD * DD * 2 + 255) & ~(size_t)255;
  // ping-pong feature buffers (bf16)
  u16* featA = (u16*)(base + off); off += ((size_t)N * DD * 2 + 255) & ~(size_t)255;
  u16* featB = (u16*)(base + off); off += ((size_t)N * DD * 2 + 255) & ~(size_t)255;

  // dtype probe + input conversion to bf16 working copies
  probe_dtype<<<1, 64, 0, stream>>>((const u32*)xe1, flag);
  cvt_in<<<(120 * DD + 255) / 256, 256, 0, stream>>>(xe1, wx1, 120 * DD, flag);
  cvt_in<<<(3 * DD + 255) / 256, 256, 0, stream>>>(xe2, wx2, 3 * DD, flag);
  cvt_in<<<(L * 6 * DD + 255) / 256, 256, 0, stream>>>(ee1, wee1, L * 6 * DD, flag);
  cvt_in<<<(L * 3 * DD + 255) / 256, 256, 0, stream>>>(ee2, wee2, L * 3 * DD, flag);
  cvt_in<<<(L * DD * 2 * DD + 255) / 256, 256, 0, stream>>>(W1, wW1, L * DD * 2 * DD, flag);
  cvt_in<<<(L * 2 * DD + 255) / 256, 256, 0, stream>>>(b1, wb1, L * 2 * DD, flag);
  cvt_in<<<(L * 2 * DD * DD + 255) / 256, 256, 0, stream>>>(W2, wW2, L * 2 * DD * DD, flag);
  cvt_in<<<(L * DD + 255) / 256, 256, 0, stream>>>(b2, wb2, L * DD, flag);
  cvt_in<<<((L - 1) * DD + 255) / 256, 256, 0, stream>>>(gam, wgam, (L - 1) * DD, flag);
  cvt_in<<<((L - 1) * DD + 255) / 256, 256, 0, stream>>>(bet, wbet, (L - 1) * DD, flag);

  // one-time per call: tables, packed weights (batched), CSR
  build_table<<<90, 256, 0, stream>>>(wee1, wee2, TBL);
  pack_B<<<dim3(64, L), 256, 0, stream>>>(wW1, Wp1, DD, 2 * DD);
  pack_B<<<dim3(64, L), 256, 0, stream>>>(wW2, Wp2, 2 * DD, DD);
  zero_int<<<(N + 255) / 256, 256, 0, stream>>>(counts, N);
  hist_kernel<<<(E + 255) / 256, 256, 0, stream>>>(ei + E, counts, E);
  scan_sums<<<NB, 256, 0, stream>>>(counts, bsum, N);
  scan_top<<<1, 64, 0, stream>>>(bsum, NB);
  scan_block<<<NB, 256, 0, stream>>>(counts, bsum, offsets, cursor, N);
  fill_csr<<<(E + 255) / 256, 256, 0, stream>>>(ei, ea, cursor, payload, E);

  // initial node features
  node_embed<<<(N * DD + 255) / 256, 256, 0, stream>>>(x, wx1, wx2, featA, N);

  float invN = 1.0f / (float)N;
  u16* fin = featA;
  u16* fout = featB;

  for (int l = 0; l < L; l++){
    layer_fused<<<nblk, 512, 0, stream>>>(
        fin, TBL + (size_t)l * 18 * DD, offsets, counts, payload,
        Wp1 + (size_t)l * DD * 2 * DD, wb1 + (size_t)l * 2 * DD,
        Wp2 + (size_t)l * 2 * DD * DD, wb2 + (size_t)l * DD,
        fout, (l < L - 1) ? part : (float*)nullptr, npart, N,
        sums, wgam + (size_t)(l > 0 ? l - 1 : 0) * DD,
        wbet + (size_t)(l > 0 ? l - 1 : 0) * DD, invN, l > 0 ? 1 : 0);

    if (l < L - 1){
      bn_reduce<<<16, 256, 0, stream>>>(part, sums, npart);
    }
    u16* t = fin; fin = fout; fout = t;
  }

  // final h is in fin (after swap); write to d_out in the proper dtype
  store_out<<<(N * DD + 255) / 256, 256, 0, stream>>>(fin, d_out, N * DD, flag);
}